// Round 13
// baseline (1052.051 us; speedup 1.0000x reference)
//
#include <hip/hip_runtime.h>
#include <stddef.h>

#define NN 100000
#define NE 800000
#define DIN 128
#define DH 512
#define MT 782   // ceil(100000/128)
#define NWG (MT * 4)      // 3128 = 8 * 391
#define CPX (NWG / 8)     // 391 chunks per XCD

typedef __attribute__((ext_vector_type(8))) short sh8;
typedef __attribute__((ext_vector_type(4))) float f32x4;

__device__ __forceinline__ unsigned short f2b(float f) {
  unsigned u = __float_as_uint(f);
  return (unsigned short)((u + 0x7FFFu + ((u >> 16) & 1u)) >> 16);
}
__device__ __forceinline__ float b2f(unsigned short s) {
  return __uint_as_float(((unsigned)s) << 16);
}

__device__ __forceinline__ void gload16(const unsigned short* g, unsigned short* l) {
  __builtin_amdgcn_global_load_lds(
      (const __attribute__((address_space(1))) void*)g,
      (__attribute__((address_space(3))) void*)l, 16, 0, 0);
}

#define SCHED_FENCE() __builtin_amdgcn_sched_barrier(0)
#define MEM_FENCE() asm volatile("" ::: "memory")
#define VMCNT(n) asm volatile("s_waitcnt vmcnt(" #n ")" ::: "memory")

// ---------------- CSR build ----------------

__global__ void k_count(const int* __restrict__ dst, int* __restrict__ cnt) {
  int i = blockIdx.x * blockDim.x + threadIdx.x;
  if (i < NE) atomicAdd(&cnt[dst[i]], 1);
}

__global__ void k_invdeg(const int* __restrict__ cnt, float* __restrict__ inv_deg) {
  int i = blockIdx.x * blockDim.x + threadIdx.x;
  if (i < NN) inv_deg[i] = 1.0f / (float)(cnt[i] > 1 ? cnt[i] : 1);
}

__global__ void k_scan1(const int* __restrict__ cnt, int* __restrict__ excl,
                        int* __restrict__ partials) {
  __shared__ int sh[256];
  int tid = threadIdx.x;
  int base = blockIdx.x * 1024 + tid * 4;
  int v[4]; int s = 0;
#pragma unroll
  for (int i = 0; i < 4; i++) { int idx = base + i; v[i] = (idx < NN) ? cnt[idx] : 0; s += v[i]; }
  sh[tid] = s; __syncthreads();
  for (int off = 1; off < 256; off <<= 1) {
    int t = (tid >= off) ? sh[tid - off] : 0;
    __syncthreads();
    sh[tid] += t;
    __syncthreads();
  }
  int run = sh[tid] - s;
#pragma unroll
  for (int i = 0; i < 4; i++) { int idx = base + i; if (idx < NN) excl[idx] = run; run += v[i]; }
  if (tid == 255) partials[blockIdx.x] = sh[255];
}

__global__ void k_scan2(int* __restrict__ partials, int* __restrict__ row_start, int nparts) {
  __shared__ int sh[128];
  int tid = threadIdx.x;
  int v = (tid < nparts) ? partials[tid] : 0;
  sh[tid] = v; __syncthreads();
  for (int off = 1; off < 128; off <<= 1) {
    int t = (tid >= off) ? sh[tid - off] : 0;
    __syncthreads();
    sh[tid] += t;
    __syncthreads();
  }
  if (tid < nparts) partials[tid] = sh[tid] - v;
  if (tid == 127) row_start[NN] = sh[127];
}

__global__ void k_scan3(int* __restrict__ excl, const int* __restrict__ partials) {
  int i = blockIdx.x * blockDim.x + threadIdx.x;
  if (i < NN) excl[i] += partials[i >> 10];
}

__global__ void k_fill(const int* __restrict__ src, const int* __restrict__ dst,
                       const int* __restrict__ row_start, int* __restrict__ cursor,
                       int* __restrict__ ssrc) {
  int i = blockIdx.x * blockDim.x + threadIdx.x;
  if (i < NE) {
    int d = dst[i];
    int pos = atomicAdd(&cursor[d], 1);
    ssrc[row_start[d] + pos] = src[i];
  }
}

// ---------------- f32 -> bf16 convert ----------------

__global__ void k_f2b(const float* __restrict__ src, unsigned short* __restrict__ dst, int n) {
  int i = (blockIdx.x * blockDim.x + threadIdx.x) * 4;
  if (i < n) {
    float4 v = *(const float4*)(src + i);
    ushort4 o;
    o.x = f2b(v.x); o.y = f2b(v.y); o.z = f2b(v.z); o.w = f2b(v.w);
    *(ushort4*)(dst + i) = o;
  }
}

// ---------------- mean aggregation (wave per node, bf16 in/out, f32 accum) ----------------

__global__ __launch_bounds__(256) void k_aggb512(
    const unsigned short* __restrict__ z, const int* __restrict__ rs,
    const int* __restrict__ ssrc, const float* __restrict__ inv_deg,
    unsigned short* __restrict__ agg) {
  int w = (blockIdx.x * blockDim.x + threadIdx.x) >> 6;
  int lane = threadIdx.x & 63;
  if (w >= NN) return;
  int e0 = rs[w], e1 = rs[w + 1];
  float acc[8] = {0, 0, 0, 0, 0, 0, 0, 0};
  int e = e0;
  for (; e + 3 < e1; e += 4) {     // 4 independent 16B gathers in flight
    int s0i = ssrc[e], s1i = ssrc[e + 1], s2i = ssrc[e + 2], s3i = ssrc[e + 3];
    sh8 v0 = *(const sh8*)(z + (size_t)s0i * DH + lane * 8);
    sh8 v1 = *(const sh8*)(z + (size_t)s1i * DH + lane * 8);
    sh8 v2 = *(const sh8*)(z + (size_t)s2i * DH + lane * 8);
    sh8 v3 = *(const sh8*)(z + (size_t)s3i * DH + lane * 8);
#pragma unroll
    for (int j = 0; j < 8; ++j)
      acc[j] += (b2f((unsigned short)v0[j]) + b2f((unsigned short)v1[j])) +
                (b2f((unsigned short)v2[j]) + b2f((unsigned short)v3[j]));
  }
  for (; e < e1; ++e) {
    int sa = ssrc[e];
    sh8 va = *(const sh8*)(z + (size_t)sa * DH + lane * 8);
#pragma unroll
    for (int j = 0; j < 8; ++j) acc[j] += b2f((unsigned short)va[j]);
  }
  float s0 = inv_deg[w];
  sh8 o;
#pragma unroll
  for (int j = 0; j < 8; ++j) o[j] = (short)f2b(acc[j] * s0);
  *(sh8*)(agg + (size_t)w * DH + lane * 8) = o;
}

__global__ __launch_bounds__(256) void k_aggb128(
    const unsigned short* __restrict__ z, const int* __restrict__ rs,
    const int* __restrict__ ssrc, const float* __restrict__ inv_deg,
    unsigned short* __restrict__ agg) {
  int w = (blockIdx.x * blockDim.x + threadIdx.x) >> 6;
  int lane = threadIdx.x & 63;
  if (w >= NN) return;
  int e0 = rs[w], e1 = rs[w + 1];
  float a0 = 0.f, a1 = 0.f;
  int e = e0;
  for (; e + 3 < e1; e += 4) {
    unsigned v0 = *(const unsigned*)(z + (size_t)ssrc[e] * DIN + lane * 2);
    unsigned v1 = *(const unsigned*)(z + (size_t)ssrc[e + 1] * DIN + lane * 2);
    unsigned v2 = *(const unsigned*)(z + (size_t)ssrc[e + 2] * DIN + lane * 2);
    unsigned v3 = *(const unsigned*)(z + (size_t)ssrc[e + 3] * DIN + lane * 2);
    a0 += (b2f((unsigned short)(v0 & 0xFFFFu)) + b2f((unsigned short)(v1 & 0xFFFFu))) +
          (b2f((unsigned short)(v2 & 0xFFFFu)) + b2f((unsigned short)(v3 & 0xFFFFu)));
    a1 += (b2f((unsigned short)(v0 >> 16)) + b2f((unsigned short)(v1 >> 16))) +
          (b2f((unsigned short)(v2 >> 16)) + b2f((unsigned short)(v3 >> 16)));
  }
  for (; e < e1; ++e) {
    unsigned va = *(const unsigned*)(z + (size_t)ssrc[e] * DIN + lane * 2);
    a0 += b2f((unsigned short)(va & 0xFFFFu));
    a1 += b2f((unsigned short)(va >> 16));
  }
  float s0 = inv_deg[w];
  unsigned o = (unsigned)f2b(a0 * s0) | ((unsigned)f2b(a1 * s0) << 16);
  *(unsigned*)(agg + (size_t)w * DIN + lane * 2) = o;
}

// ================= k_gemm1: 128x128 3-buf DMA pipeline (R6/R9 baseline) =========

__device__ __forceinline__ void stage_tile(
    unsigned short* ldsA, unsigned short* ldsB,
    const unsigned short* __restrict__ A, int sA, int m0,
    const unsigned short* __restrict__ B, int sB, int n0,
    int k0, int tid) {
  const int w = tid >> 6, l = tid & 63;
  const int kc = (l & 3) * 8;
  const int rsub = l >> 2;
#pragma unroll
  for (int i = 0; i < 2; ++i) {
    int rl = w * 32 + i * 16 + rsub;
    int ra = m0 + rl; if (ra >= NN) ra = NN - 1;
    gload16(A + (size_t)ra * sA + k0 + kc, ldsA + (size_t)(w * 32 + i * 16) * 32);
    gload16(B + (size_t)(n0 + rl) * sB + k0 + kc, ldsB + (size_t)(w * 32 + i * 16) * 32);
  }
}

__device__ __forceinline__ void mfma_step(
    const unsigned short* As, const unsigned short* Bs,
    int wr, int wc, int r16, int kg, f32x4 (&acc)[4][4]) {
  sh8 af[4], bf[4];
#pragma unroll
  for (int i = 0; i < 4; ++i)
    af[i] = *(const sh8*)&As[(wr + i * 16 + r16) * 32 + kg * 8];
#pragma unroll
  for (int j = 0; j < 4; ++j)
    bf[j] = *(const sh8*)&Bs[(wc + j * 16 + r16) * 32 + kg * 8];
#pragma unroll
  for (int i = 0; i < 4; ++i)
#pragma unroll
    for (int j = 0; j < 4; ++j)
      acc[i][j] = __builtin_amdgcn_mfma_f32_16x16x32_bf16(af[i], bf[j], acc[i][j], 0, 0, 0);
}

#define PIPE_WAIT(s, S)                 \
  do {                                  \
    if ((s) < (S) - 2) VMCNT(8);        \
    else if ((s) == (S) - 2) VMCNT(4);  \
    else VMCNT(0);                      \
    SCHED_FENCE();                      \
    __builtin_amdgcn_s_barrier();       \
    MEM_FENCE(); SCHED_FENCE();         \
  } while (0)

#define PIPE_END()                      \
  do {                                  \
    SCHED_FENCE();                      \
    __builtin_amdgcn_s_barrier();       \
    MEM_FENCE(); SCHED_FENCE();         \
  } while (0)

__global__ __launch_bounds__(256, 2) void k_gemm1(
    const unsigned short* __restrict__ ag, const unsigned short* __restrict__ xb,
    const unsigned short* __restrict__ Wl1, const unsigned short* __restrict__ Wr1,
    const unsigned short* __restrict__ Ww, const unsigned short* __restrict__ Ww2,
    const float* __restrict__ bl1, const float* __restrict__ bw,
    const float* __restrict__ bw2, const float* __restrict__ aptr,
    unsigned short* __restrict__ z2o, unsigned short* __restrict__ z3po) {
  __shared__ __align__(16) unsigned short As[3][128 * 32];
  __shared__ __align__(16) unsigned short Bs[3][128 * 32];
  const int tid = threadIdx.x;
  const int b = blockIdx.x;
  const int L = (b & 7) * CPX + (b >> 3);
  const int m0 = (L >> 2) * 128, n0 = (L & 3) * 128;
  const int wid = tid >> 6, lane = tid & 63;
  const int r16 = lane & 15, kg = lane >> 4;
  const int wr = (wid >> 1) * 64, wc = (wid & 1) * 64;

  f32x4 a0[4][4], a1[4][4], a2[4][4];
#pragma unroll
  for (int i = 0; i < 4; ++i)
#pragma unroll
    for (int j = 0; j < 4; ++j) { a0[i][j] = 0.f; a1[i][j] = 0.f; a2[i][j] = 0.f; }

  auto stage = [&](int s, int buf) {
    const int seg = s >> 2, k0 = (s & 3) * 32;
    const unsigned short* Ap = (seg == 0) ? ag : xb;
    const unsigned short* Bp = (seg == 0) ? Wl1 : (seg == 1) ? Wr1 : (seg == 2) ? Ww : Ww2;
    stage_tile(As[buf], Bs[buf], Ap, DIN, m0, Bp, DIN, n0, k0, tid);
  };

  stage(0, 0);
  stage(1, 1);
  int cur = 0, nxt = 2;
  for (int s = 0; s < 16; ++s) {
    if (s + 2 < 16) stage(s + 2, nxt);
    PIPE_WAIT(s, 16);
    const int seg = s >> 2;
    __builtin_amdgcn_s_setprio(1);
    if (seg <= 1)      mfma_step(As[cur], Bs[cur], wr, wc, r16, kg, a0);
    else if (seg == 2) mfma_step(As[cur], Bs[cur], wr, wc, r16, kg, a1);
    else               mfma_step(As[cur], Bs[cur], wr, wc, r16, kg, a2);
    __builtin_amdgcn_s_setprio(0);
    PIPE_END();
    cur = (cur == 2) ? 0 : cur + 1;
    nxt = (nxt == 2) ? 0 : nxt + 1;
  }

  const float aval = aptr[0];
#pragma unroll
  for (int i = 0; i < 4; ++i) {
    const int mbase = m0 + wr + i * 16 + kg * 4;
#pragma unroll
    for (int j = 0; j < 4; ++j) {
      const int col = n0 + wc + j * 16 + r16;
      const float b1 = bl1[col], b2 = bw[col], b3 = bw2[col];
#pragma unroll
      for (int r = 0; r < 4; ++r) {
        const int m = mbase + r;
        if (m >= NN) continue;
        float h1 = a0[i][j][r] + b1;
        h1 = h1 > 0.f ? h1 : aval * h1;
        z2o[(size_t)m * DH + col] = f2b(h1 + a1[i][j][r] + b2);
        z3po[(size_t)m * DH + col] = f2b(h1 + a2[i][j][r] + b3);
      }
    }
  }
}

// ========== k_rg23: reg-staged 128x128 GEMM, XCD L-swizzle grid (R9), depth-2 prefetch ==========

template <bool LAST>
__global__ __launch_bounds__(256) void k_rg23(
    const unsigned short* __restrict__ Aag, const unsigned short* __restrict__ Az,
    const unsigned short* __restrict__ Wl, const unsigned short* __restrict__ Wr,
    const float* __restrict__ bl, const float* __restrict__ aptr,
    const unsigned short* __restrict__ z3p, void* __restrict__ outp) {
  __shared__ __align__(16) unsigned short As[128 * 32];
  __shared__ __align__(16) unsigned short Bs[128 * 32];
  const int tid = threadIdx.x;
  const int b = blockIdx.x;
  const int L = (b & 7) * CPX + (b >> 3);   // XCD-contiguous chunks (R9: FETCH 171 MB)
  const int m0 = (L >> 2) * 128, n0 = (L & 3) * 128;
  const int wid = tid >> 6, lane = tid & 63;
  const int r16 = lane & 15, kg = lane >> 4;
  const int wr = (wid >> 1) * 64, wc = (wid & 1) * 64;
  const int rA = tid >> 2;        // 0..63
  const int cA = (tid & 3) * 8;   // k-element offset

  f32x4 acc[4][4];
#pragma unroll
  for (int i = 0; i < 4; ++i)
#pragma unroll
    for (int j = 0; j < 4; ++j) acc[i][j] = 0.f;

  auto ldA = [&](int s, int r) -> sh8 {
    const unsigned short* A = (s < 16) ? Aag : Az;
    int row = m0 + r; if (row >= NN) row = NN - 1;
    return *(const sh8*)(A + (size_t)row * DH + (s & 15) * 32 + cA);
  };
  auto ldB = [&](int s, int r) -> sh8 {
    const unsigned short* W = (s < 16) ? Wl : Wr;
    return *(const sh8*)(W + (size_t)(n0 + r) * DH + (s & 15) * 32 + cA);
  };

  // depth-2 prefetch: two register sets; loads for step s+2 issue at step s.
  sh8 va0 = ldA(0, rA), va1 = ldA(0, rA + 64);
  sh8 vb0 = ldB(0, rA), vb1 = ldB(0, rA + 64);
  sh8 wa0 = ldA(1, rA), wa1 = ldA(1, rA + 64);
  sh8 wb0 = ldB(1, rA), wb1 = ldB(1, rA + 64);

  for (int s = 0; s < 32; s += 2) {
    // even step s (data in va/vb)
    __syncthreads();
    *(sh8*)&As[rA * 32 + cA] = va0;
    *(sh8*)&As[(rA + 64) * 32 + cA] = va1;
    *(sh8*)&Bs[rA * 32 + cA] = vb0;
    *(sh8*)&Bs[(rA + 64) * 32 + cA] = vb1;
    __syncthreads();
    if (s + 2 < 32) {
      va0 = ldA(s + 2, rA); va1 = ldA(s + 2, rA + 64);
      vb0 = ldB(s + 2, rA); vb1 = ldB(s + 2, rA + 64);
    }
    mfma_step(As, Bs, wr, wc, r16, kg, acc);
    // odd step s+1 (data in wa/wb)
    __syncthreads();
    *(sh8*)&As[rA * 32 + cA] = wa0;
    *(sh8*)&As[(rA + 64) * 32 + cA] = wa1;
    *(sh8*)&Bs[rA * 32 + cA] = wb0;
    *(sh8*)&Bs[(rA + 64) * 32 + cA] = wb1;
    __syncthreads();
    if (s + 3 < 32) {
      wa0 = ldA(s + 3, rA); wa1 = ldA(s + 3, rA + 64);
      wb0 = ldB(s + 3, rA); wb1 = ldB(s + 3, rA + 64);
    }
    mfma_step(As, Bs, wr, wc, r16, kg, acc);
  }

  const float aval = aptr[0];
  float* outf = (float*)outp;
  unsigned short* outb = (unsigned short*)outp;
#pragma unroll
  for (int i = 0; i < 4; ++i) {
    const int mbase = m0 + wr + i * 16 + kg * 4;
#pragma unroll
    for (int j = 0; j < 4; ++j) {
      const int col = n0 + wc + j * 16 + r16;
      const float bv = bl[col];
#pragma unroll
      for (int r = 0; r < 4; ++r) {
        const int m = mbase + r;
        if (m >= NN) continue;
        float h = acc[i][j][r] + bv;
        h = h > 0.f ? h : aval * h;
        if constexpr (LAST) {
          outf[(size_t)m * DH + col] = h;
        } else {
          outb[(size_t)m * DH + col] = f2b(h + b2f(z3p[(size_t)m * DH + col]));
        }
      }
    }
  }
}

// ---------------- launch ----------------

extern "C" void kernel_launch(void* const* d_in, const int* in_sizes, int n_in,
                              void* d_out, int out_size, void* d_ws, size_t ws_size,
                              hipStream_t stream) {
  const float* x = (const float*)d_in[0];
  const int* ei = (const int*)d_in[1];
  const float* Wl1 = (const float*)d_in[2];
  const float* bl1 = (const float*)d_in[3];
  const float* Wr1 = (const float*)d_in[4];
  const float* Wl2 = (const float*)d_in[5];
  const float* bl2 = (const float*)d_in[6];
  const float* Wr2 = (const float*)d_in[7];
  const float* Wl3 = (const float*)d_in[8];
  const float* bl3 = (const float*)d_in[9];
  const float* Wr3 = (const float*)d_in[10];
  const float* Ww  = (const float*)d_in[11];
  const float* bw  = (const float*)d_in[12];
  const float* Ww2 = (const float*)d_in[13];
  const float* bw2 = (const float*)d_in[14];
  const float* ap  = (const float*)d_in[15];
  float* out = (float*)d_out;

  const size_t MP = 100096;  // 782*128
  char* w = (char*)d_ws;
  size_t off = 0;
  unsigned short* xb   = (unsigned short*)(w + off); off += MP * DIN * 2;
  unsigned short* ag1  = (unsigned short*)(w + off); off += MP * DIN * 2;
  unsigned short* agb  = (unsigned short*)(w + off); off += MP * DH * 2;
  unsigned short* zb   = (unsigned short*)(w + off); off += MP * DH * 2;   // z2
  unsigned short* zc   = (unsigned short*)(w + off); off += MP * DH * 2;   // z3
  unsigned short* z3pb = (unsigned short*)(w + off); off += MP * DH * 2;
  unsigned short* Wl1b = (unsigned short*)(w + off); off += (size_t)DH * DIN * 2;
  unsigned short* Wr1b = (unsigned short*)(w + off); off += (size_t)DH * DIN * 2;
  unsigned short* Wwb  = (unsigned short*)(w + off); off += (size_t)DH * DIN * 2;
  unsigned short* Ww2b = (unsigned short*)(w + off); off += (size_t)DH * DIN * 2;
  unsigned short* Wl2b = (unsigned short*)(w + off); off += (size_t)DH * DH * 2;
  unsigned short* Wr2b = (unsigned short*)(w + off); off += (size_t)DH * DH * 2;
  unsigned short* Wl3b = (unsigned short*)(w + off); off += (size_t)DH * DH * 2;
  unsigned short* Wr3b = (unsigned short*)(w + off); off += (size_t)DH * DH * 2;
  float* inv_deg = (float*)(w + off); off += (size_t)NN * 4;
  int* row_start = (int*)(w + off); off += (size_t)(NN + 1) * 4;
  int* cursor = (int*)(w + off); off += (size_t)NN * 4;
  int* ssrc = (int*)(w + off); off += (size_t)NE * 4;
  int* partials = (int*)(w + off); off += 512;

  const int* esrc = ei;
  const int* edst = ei + NE;

  // CSR build (once, reused by all 3 layers)
  hipMemsetAsync(cursor, 0, NN * 4, stream);
  k_count<<<(NE + 255) / 256, 256, 0, stream>>>(edst, cursor);
  k_invdeg<<<(NN + 255) / 256, 256, 0, stream>>>(cursor, inv_deg);
  k_scan1<<<(NN + 1023) / 1024, 256, 0, stream>>>(cursor, row_start, partials);
  k_scan2<<<1, 128, 0, stream>>>(partials, row_start, (NN + 1023) / 1024);
  k_scan3<<<(NN + 255) / 256, 256, 0, stream>>>(row_start, partials);
  hipMemsetAsync(cursor, 0, NN * 4, stream);
  k_fill<<<(NE + 255) / 256, 256, 0, stream>>>(esrc, edst, row_start, cursor, ssrc);

  // bf16 conversions
  const int WK = DH * DIN;
  const int WB = DH * DH;
  k_f2b<<<(WK / 4 + 255) / 256, 256, 0, stream>>>(Wl1, Wl1b, WK);
  k_f2b<<<(WK / 4 + 255) / 256, 256, 0, stream>>>(Wr1, Wr1b, WK);
  k_f2b<<<(WK / 4 + 255) / 256, 256, 0, stream>>>(Ww,  Wwb,  WK);
  k_f2b<<<(WK / 4 + 255) / 256, 256, 0, stream>>>(Ww2, Ww2b, WK);
  k_f2b<<<(WB / 4 + 255) / 256, 256, 0, stream>>>(Wl2, Wl2b, WB);
  k_f2b<<<(WB / 4 + 255) / 256, 256, 0, stream>>>(Wr2, Wr2b, WB);
  k_f2b<<<(WB / 4 + 255) / 256, 256, 0, stream>>>(Wl3, Wl3b, WB);
  k_f2b<<<(WB / 4 + 255) / 256, 256, 0, stream>>>(Wr3, Wr3b, WB);
  k_f2b<<<(NN * DIN / 4 + 255) / 256, 256, 0, stream>>>(x, xb, NN * DIN);

  // agg1 = mean(x) ; gemm1 -> z2 (zb), z3p (z3pb); h1 never materialized
  k_aggb128<<<(NN + 3) / 4, 256, 0, stream>>>(xb, row_start, ssrc, inv_deg, ag1);
  k_gemm1<<<NWG, 256, 0, stream>>>(ag1, xb, Wl1b, Wr1b, Wwb, Ww2b, bl1, bw, bw2, ap,
                                   zb, z3pb);
  // layer 2: agg2 = mean(z2); z3 = prelu(agg2@Wl2 + z2@Wr2 + bl2) + z3p -> zc
  k_aggb512<<<(NN + 3) / 4, 256, 0, stream>>>(zb, row_start, ssrc, inv_deg, agb);
  k_rg23<false><<<NWG, 256, 0, stream>>>(agb, zb, Wl2b, Wr2b, bl2, ap, z3pb, zc);
  // layer 3: agg3 = mean(z3); out = prelu(agg3@Wl3 + z3@Wr3 + bl3) -> f32 d_out
  k_aggb512<<<(NN + 3) / 4, 256, 0, stream>>>(zc, row_start, ssrc, inv_deg, agb);
  k_rg23<true><<<NWG, 256, 0, stream>>>(agb, zc, Wl3b, Wr3b, bl3, ap, nullptr, out);
}

// Round 14
// 989.252 us; speedup vs baseline: 1.0635x; 1.0635x over previous
//
#include <hip/hip_runtime.h>
#include <stddef.h>

#define NN 100000
#define NE 800000
#define DIN 128
#define DH 512
#define MT 782   // ceil(100000/128)
#define NWG (MT * 4)      // 3128 = 8 * 391
#define CPX (NWG / 8)     // 391 chunks per XCD

typedef __attribute__((ext_vector_type(8))) short sh8;
typedef __attribute__((ext_vector_type(4))) float f32x4;

__device__ __forceinline__ unsigned short f2b(float f) {
  unsigned u = __float_as_uint(f);
  return (unsigned short)((u + 0x7FFFu + ((u >> 16) & 1u)) >> 16);
}
__device__ __forceinline__ float b2f(unsigned short s) {
  return __uint_as_float(((unsigned)s) << 16);
}

__device__ __forceinline__ void gload16(const unsigned short* g, unsigned short* l) {
  __builtin_amdgcn_global_load_lds(
      (const __attribute__((address_space(1))) void*)g,
      (__attribute__((address_space(3))) void*)l, 16, 0, 0);
}

#define SCHED_FENCE() __builtin_amdgcn_sched_barrier(0)
#define MEM_FENCE() asm volatile("" ::: "memory")
#define VMCNT(n) asm volatile("s_waitcnt vmcnt(" #n ")" ::: "memory")

// ---------------- CSR build ----------------

__global__ void k_count(const int* __restrict__ dst, int* __restrict__ cnt) {
  int i = blockIdx.x * blockDim.x + threadIdx.x;
  if (i < NE) atomicAdd(&cnt[dst[i]], 1);
}

__global__ void k_invdeg(const int* __restrict__ cnt, float* __restrict__ inv_deg) {
  int i = blockIdx.x * blockDim.x + threadIdx.x;
  if (i < NN) inv_deg[i] = 1.0f / (float)(cnt[i] > 1 ? cnt[i] : 1);
}

__global__ void k_scan1(const int* __restrict__ cnt, int* __restrict__ excl,
                        int* __restrict__ partials) {
  __shared__ int sh[256];
  int tid = threadIdx.x;
  int base = blockIdx.x * 1024 + tid * 4;
  int v[4]; int s = 0;
#pragma unroll
  for (int i = 0; i < 4; i++) { int idx = base + i; v[i] = (idx < NN) ? cnt[idx] : 0; s += v[i]; }
  sh[tid] = s; __syncthreads();
  for (int off = 1; off < 256; off <<= 1) {
    int t = (tid >= off) ? sh[tid - off] : 0;
    __syncthreads();
    sh[tid] += t;
    __syncthreads();
  }
  int run = sh[tid] - s;
#pragma unroll
  for (int i = 0; i < 4; i++) { int idx = base + i; if (idx < NN) excl[idx] = run; run += v[i]; }
  if (tid == 255) partials[blockIdx.x] = sh[255];
}

__global__ void k_scan2(int* __restrict__ partials, int* __restrict__ row_start, int nparts) {
  __shared__ int sh[128];
  int tid = threadIdx.x;
  int v = (tid < nparts) ? partials[tid] : 0;
  sh[tid] = v; __syncthreads();
  for (int off = 1; off < 128; off <<= 1) {
    int t = (tid >= off) ? sh[tid - off] : 0;
    __syncthreads();
    sh[tid] += t;
    __syncthreads();
  }
  if (tid < nparts) partials[tid] = sh[tid] - v;
  if (tid == 127) row_start[NN] = sh[127];
}

__global__ void k_scan3(int* __restrict__ excl, const int* __restrict__ partials) {
  int i = blockIdx.x * blockDim.x + threadIdx.x;
  if (i < NN) excl[i] += partials[i >> 10];
}

__global__ void k_fill(const int* __restrict__ src, const int* __restrict__ dst,
                       const int* __restrict__ row_start, int* __restrict__ cursor,
                       int* __restrict__ ssrc) {
  int i = blockIdx.x * blockDim.x + threadIdx.x;
  if (i < NE) {
    int d = dst[i];
    int pos = atomicAdd(&cursor[d], 1);
    ssrc[row_start[d] + pos] = src[i];
  }
}

// ---------------- f32 -> bf16 convert ----------------

__global__ void k_f2b(const float* __restrict__ src, unsigned short* __restrict__ dst, int n) {
  int i = (blockIdx.x * blockDim.x + threadIdx.x) * 4;
  if (i < n) {
    float4 v = *(const float4*)(src + i);
    ushort4 o;
    o.x = f2b(v.x); o.y = f2b(v.y); o.z = f2b(v.z); o.w = f2b(v.w);
    *(ushort4*)(dst + i) = o;
  }
}

// ---------------- mean aggregation (wave per node, bf16 in/out, f32 accum) ----------------

__global__ __launch_bounds__(256) void k_aggb512(
    const unsigned short* __restrict__ z, const int* __restrict__ rs,
    const int* __restrict__ ssrc, const float* __restrict__ inv_deg,
    unsigned short* __restrict__ agg) {
  int w = (blockIdx.x * blockDim.x + threadIdx.x) >> 6;
  int lane = threadIdx.x & 63;
  if (w >= NN) return;
  int e0 = rs[w], e1 = rs[w + 1];
  float acc[8] = {0, 0, 0, 0, 0, 0, 0, 0};
  int e = e0;
  for (; e + 3 < e1; e += 4) {     // 4 independent 16B gathers in flight
    int s0i = ssrc[e], s1i = ssrc[e + 1], s2i = ssrc[e + 2], s3i = ssrc[e + 3];
    sh8 v0 = *(const sh8*)(z + (size_t)s0i * DH + lane * 8);
    sh8 v1 = *(const sh8*)(z + (size_t)s1i * DH + lane * 8);
    sh8 v2 = *(const sh8*)(z + (size_t)s2i * DH + lane * 8);
    sh8 v3 = *(const sh8*)(z + (size_t)s3i * DH + lane * 8);
#pragma unroll
    for (int j = 0; j < 8; ++j)
      acc[j] += (b2f((unsigned short)v0[j]) + b2f((unsigned short)v1[j])) +
                (b2f((unsigned short)v2[j]) + b2f((unsigned short)v3[j]));
  }
  for (; e < e1; ++e) {
    int sa = ssrc[e];
    sh8 va = *(const sh8*)(z + (size_t)sa * DH + lane * 8);
#pragma unroll
    for (int j = 0; j < 8; ++j) acc[j] += b2f((unsigned short)va[j]);
  }
  float s0 = inv_deg[w];
  sh8 o;
#pragma unroll
  for (int j = 0; j < 8; ++j) o[j] = (short)f2b(acc[j] * s0);
  *(sh8*)(agg + (size_t)w * DH + lane * 8) = o;
}

__global__ __launch_bounds__(256) void k_aggb128(
    const unsigned short* __restrict__ z, const int* __restrict__ rs,
    const int* __restrict__ ssrc, const float* __restrict__ inv_deg,
    unsigned short* __restrict__ agg) {
  int w = (blockIdx.x * blockDim.x + threadIdx.x) >> 6;
  int lane = threadIdx.x & 63;
  if (w >= NN) return;
  int e0 = rs[w], e1 = rs[w + 1];
  float a0 = 0.f, a1 = 0.f;
  int e = e0;
  for (; e + 3 < e1; e += 4) {
    unsigned v0 = *(const unsigned*)(z + (size_t)ssrc[e] * DIN + lane * 2);
    unsigned v1 = *(const unsigned*)(z + (size_t)ssrc[e + 1] * DIN + lane * 2);
    unsigned v2 = *(const unsigned*)(z + (size_t)ssrc[e + 2] * DIN + lane * 2);
    unsigned v3 = *(const unsigned*)(z + (size_t)ssrc[e + 3] * DIN + lane * 2);
    a0 += (b2f((unsigned short)(v0 & 0xFFFFu)) + b2f((unsigned short)(v1 & 0xFFFFu))) +
          (b2f((unsigned short)(v2 & 0xFFFFu)) + b2f((unsigned short)(v3 & 0xFFFFu)));
    a1 += (b2f((unsigned short)(v0 >> 16)) + b2f((unsigned short)(v1 >> 16))) +
          (b2f((unsigned short)(v2 >> 16)) + b2f((unsigned short)(v3 >> 16)));
  }
  for (; e < e1; ++e) {
    unsigned va = *(const unsigned*)(z + (size_t)ssrc[e] * DIN + lane * 2);
    a0 += b2f((unsigned short)(va & 0xFFFFu));
    a1 += b2f((unsigned short)(va >> 16));
  }
  float s0 = inv_deg[w];
  unsigned o = (unsigned)f2b(a0 * s0) | ((unsigned)f2b(a1 * s0) << 16);
  *(unsigned*)(agg + (size_t)w * DIN + lane * 2) = o;
}

// ================= k_gemm1: 128x128 3-buf DMA pipeline (R6/R9 baseline) =========

__device__ __forceinline__ void stage_tile(
    unsigned short* ldsA, unsigned short* ldsB,
    const unsigned short* __restrict__ A, int sA, int m0,
    const unsigned short* __restrict__ B, int sB, int n0,
    int k0, int tid) {
  const int w = tid >> 6, l = tid & 63;
  const int kc = (l & 3) * 8;
  const int rsub = l >> 2;
#pragma unroll
  for (int i = 0; i < 2; ++i) {
    int rl = w * 32 + i * 16 + rsub;
    int ra = m0 + rl; if (ra >= NN) ra = NN - 1;
    gload16(A + (size_t)ra * sA + k0 + kc, ldsA + (size_t)(w * 32 + i * 16) * 32);
    gload16(B + (size_t)(n0 + rl) * sB + k0 + kc, ldsB + (size_t)(w * 32 + i * 16) * 32);
  }
}

__device__ __forceinline__ void mfma_step(
    const unsigned short* As, const unsigned short* Bs,
    int wr, int wc, int r16, int kg, f32x4 (&acc)[4][4]) {
  sh8 af[4], bf[4];
#pragma unroll
  for (int i = 0; i < 4; ++i)
    af[i] = *(const sh8*)&As[(wr + i * 16 + r16) * 32 + kg * 8];
#pragma unroll
  for (int j = 0; j < 4; ++j)
    bf[j] = *(const sh8*)&Bs[(wc + j * 16 + r16) * 32 + kg * 8];
#pragma unroll
  for (int i = 0; i < 4; ++i)
#pragma unroll
    for (int j = 0; j < 4; ++j)
      acc[i][j] = __builtin_amdgcn_mfma_f32_16x16x32_bf16(af[i], bf[j], acc[i][j], 0, 0, 0);
}

#define PIPE_WAIT(s, S)                 \
  do {                                  \
    if ((s) < (S) - 2) VMCNT(8);        \
    else if ((s) == (S) - 2) VMCNT(4);  \
    else VMCNT(0);                      \
    SCHED_FENCE();                      \
    __builtin_amdgcn_s_barrier();       \
    MEM_FENCE(); SCHED_FENCE();         \
  } while (0)

#define PIPE_END()                      \
  do {                                  \
    SCHED_FENCE();                      \
    __builtin_amdgcn_s_barrier();       \
    MEM_FENCE(); SCHED_FENCE();         \
  } while (0)

__global__ __launch_bounds__(256, 2) void k_gemm1(
    const unsigned short* __restrict__ ag, const unsigned short* __restrict__ xb,
    const unsigned short* __restrict__ Wl1, const unsigned short* __restrict__ Wr1,
    const unsigned short* __restrict__ Ww, const unsigned short* __restrict__ Ww2,
    const float* __restrict__ bl1, const float* __restrict__ bw,
    const float* __restrict__ bw2, const float* __restrict__ aptr,
    unsigned short* __restrict__ z2o, unsigned short* __restrict__ z3po) {
  __shared__ __align__(16) unsigned short As[3][128 * 32];
  __shared__ __align__(16) unsigned short Bs[3][128 * 32];
  const int tid = threadIdx.x;
  const int b = blockIdx.x;
  const int L = (b & 7) * CPX + (b >> 3);
  const int m0 = (L >> 2) * 128, n0 = (L & 3) * 128;
  const int wid = tid >> 6, lane = tid & 63;
  const int r16 = lane & 15, kg = lane >> 4;
  const int wr = (wid >> 1) * 64, wc = (wid & 1) * 64;

  f32x4 a0[4][4], a1[4][4], a2[4][4];
#pragma unroll
  for (int i = 0; i < 4; ++i)
#pragma unroll
    for (int j = 0; j < 4; ++j) { a0[i][j] = 0.f; a1[i][j] = 0.f; a2[i][j] = 0.f; }

  auto stage = [&](int s, int buf) {
    const int seg = s >> 2, k0 = (s & 3) * 32;
    const unsigned short* Ap = (seg == 0) ? ag : xb;
    const unsigned short* Bp = (seg == 0) ? Wl1 : (seg == 1) ? Wr1 : (seg == 2) ? Ww : Ww2;
    stage_tile(As[buf], Bs[buf], Ap, DIN, m0, Bp, DIN, n0, k0, tid);
  };

  stage(0, 0);
  stage(1, 1);
  int cur = 0, nxt = 2;
  for (int s = 0; s < 16; ++s) {
    if (s + 2 < 16) stage(s + 2, nxt);
    PIPE_WAIT(s, 16);
    const int seg = s >> 2;
    __builtin_amdgcn_s_setprio(1);
    if (seg <= 1)      mfma_step(As[cur], Bs[cur], wr, wc, r16, kg, a0);
    else if (seg == 2) mfma_step(As[cur], Bs[cur], wr, wc, r16, kg, a1);
    else               mfma_step(As[cur], Bs[cur], wr, wc, r16, kg, a2);
    __builtin_amdgcn_s_setprio(0);
    PIPE_END();
    cur = (cur == 2) ? 0 : cur + 1;
    nxt = (nxt == 2) ? 0 : nxt + 1;
  }

  const float aval = aptr[0];
#pragma unroll
  for (int i = 0; i < 4; ++i) {
    const int mbase = m0 + wr + i * 16 + kg * 4;
#pragma unroll
    for (int j = 0; j < 4; ++j) {
      const int col = n0 + wc + j * 16 + r16;
      const float b1 = bl1[col], b2 = bw[col], b3 = bw2[col];
#pragma unroll
      for (int r = 0; r < 4; ++r) {
        const int m = mbase + r;
        if (m >= NN) continue;
        float h1 = a0[i][j][r] + b1;
        h1 = h1 > 0.f ? h1 : aval * h1;
        z2o[(size_t)m * DH + col] = f2b(h1 + a1[i][j][r] + b2);
        z3po[(size_t)m * DH + col] = f2b(h1 + a2[i][j][r] + b3);
      }
    }
  }
}

// ========== k_rg23: reg-staged 128x128 GEMM, XCD L-swizzle grid (exact R9 best) ==========

template <bool LAST>
__global__ __launch_bounds__(256) void k_rg23(
    const unsigned short* __restrict__ Aag, const unsigned short* __restrict__ Az,
    const unsigned short* __restrict__ Wl, const unsigned short* __restrict__ Wr,
    const float* __restrict__ bl, const float* __restrict__ aptr,
    const unsigned short* __restrict__ z3p, void* __restrict__ outp) {
  __shared__ __align__(16) unsigned short As[128 * 32];
  __shared__ __align__(16) unsigned short Bs[128 * 32];
  const int tid = threadIdx.x;
  const int b = blockIdx.x;
  const int L = (b & 7) * CPX + (b >> 3);   // XCD-contiguous chunks (R9: FETCH 171 MB)
  const int m0 = (L >> 2) * 128, n0 = (L & 3) * 128;
  const int wid = tid >> 6, lane = tid & 63;
  const int r16 = lane & 15, kg = lane >> 4;
  const int wr = (wid >> 1) * 64, wc = (wid & 1) * 64;
  const int rA = tid >> 2;        // 0..63
  const int cA = (tid & 3) * 8;   // k-element offset

  f32x4 acc[4][4];
#pragma unroll
  for (int i = 0; i < 4; ++i)
#pragma unroll
    for (int j = 0; j < 4; ++j) acc[i][j] = 0.f;

  auto ldA = [&](int s, int r) -> sh8 {
    const unsigned short* A = (s < 16) ? Aag : Az;
    int row = m0 + r; if (row >= NN) row = NN - 1;
    return *(const sh8*)(A + (size_t)row * DH + (s & 15) * 32 + cA);
  };
  auto ldB = [&](int s, int r) -> sh8 {
    const unsigned short* W = (s < 16) ? Wl : Wr;
    return *(const sh8*)(W + (size_t)(n0 + r) * DH + (s & 15) * 32 + cA);
  };

  sh8 va0 = ldA(0, rA), va1 = ldA(0, rA + 64);
  sh8 vb0 = ldB(0, rA), vb1 = ldB(0, rA + 64);

  for (int s = 0; s < 32; ++s) {
    __syncthreads();
    *(sh8*)&As[rA * 32 + cA] = va0;
    *(sh8*)&As[(rA + 64) * 32 + cA] = va1;
    *(sh8*)&Bs[rA * 32 + cA] = vb0;
    *(sh8*)&Bs[(rA + 64) * 32 + cA] = vb1;
    __syncthreads();
    if (s + 1 < 32) {  // prefetch next step into regs, overlaps MFMA below
      va0 = ldA(s + 1, rA); va1 = ldA(s + 1, rA + 64);
      vb0 = ldB(s + 1, rA); vb1 = ldB(s + 1, rA + 64);
    }
    mfma_step(As, Bs, wr, wc, r16, kg, acc);
  }

  const float aval = aptr[0];
  float* outf = (float*)outp;
  unsigned short* outb = (unsigned short*)outp;
#pragma unroll
  for (int i = 0; i < 4; ++i) {
    const int mbase = m0 + wr + i * 16 + kg * 4;
#pragma unroll
    for (int j = 0; j < 4; ++j) {
      const int col = n0 + wc + j * 16 + r16;
      const float bv = bl[col];
#pragma unroll
      for (int r = 0; r < 4; ++r) {
        const int m = mbase + r;
        if (m >= NN) continue;
        float h = acc[i][j][r] + bv;
        h = h > 0.f ? h : aval * h;
        if constexpr (LAST) {
          outf[(size_t)m * DH + col] = h;
        } else {
          outb[(size_t)m * DH + col] = f2b(h + b2f(z3p[(size_t)m * DH + col]));
        }
      }
    }
  }
}

// ---------------- launch ----------------

extern "C" void kernel_launch(void* const* d_in, const int* in_sizes, int n_in,
                              void* d_out, int out_size, void* d_ws, size_t ws_size,
                              hipStream_t stream) {
  const float* x = (const float*)d_in[0];
  const int* ei = (const int*)d_in[1];
  const float* Wl1 = (const float*)d_in[2];
  const float* bl1 = (const float*)d_in[3];
  const float* Wr1 = (const float*)d_in[4];
  const float* Wl2 = (const float*)d_in[5];
  const float* bl2 = (const float*)d_in[6];
  const float* Wr2 = (const float*)d_in[7];
  const float* Wl3 = (const float*)d_in[8];
  const float* bl3 = (const float*)d_in[9];
  const float* Wr3 = (const float*)d_in[10];
  const float* Ww  = (const float*)d_in[11];
  const float* bw  = (const float*)d_in[12];
  const float* Ww2 = (const float*)d_in[13];
  const float* bw2 = (const float*)d_in[14];
  const float* ap  = (const float*)d_in[15];
  float* out = (float*)d_out;

  const size_t MP = 100096;  // 782*128
  char* w = (char*)d_ws;
  size_t off = 0;
  unsigned short* xb   = (unsigned short*)(w + off); off += MP * DIN * 2;
  unsigned short* ag1  = (unsigned short*)(w + off); off += MP * DIN * 2;
  unsigned short* agb  = (unsigned short*)(w + off); off += MP * DH * 2;
  unsigned short* zb   = (unsigned short*)(w + off); off += MP * DH * 2;   // z2
  unsigned short* zc   = (unsigned short*)(w + off); off += MP * DH * 2;   // z3
  unsigned short* z3pb = (unsigned short*)(w + off); off += MP * DH * 2;
  unsigned short* Wl1b = (unsigned short*)(w + off); off += (size_t)DH * DIN * 2;
  unsigned short* Wr1b = (unsigned short*)(w + off); off += (size_t)DH * DIN * 2;
  unsigned short* Wwb  = (unsigned short*)(w + off); off += (size_t)DH * DIN * 2;
  unsigned short* Ww2b = (unsigned short*)(w + off); off += (size_t)DH * DIN * 2;
  unsigned short* Wl2b = (unsigned short*)(w + off); off += (size_t)DH * DH * 2;
  unsigned short* Wr2b = (unsigned short*)(w + off); off += (size_t)DH * DH * 2;
  unsigned short* Wl3b = (unsigned short*)(w + off); off += (size_t)DH * DH * 2;
  unsigned short* Wr3b = (unsigned short*)(w + off); off += (size_t)DH * DH * 2;
  float* inv_deg = (float*)(w + off); off += (size_t)NN * 4;
  int* row_start = (int*)(w + off); off += (size_t)(NN + 1) * 4;
  int* cursor = (int*)(w + off); off += (size_t)NN * 4;
  int* ssrc = (int*)(w + off); off += (size_t)NE * 4;
  int* partials = (int*)(w + off); off += 512;

  const int* esrc = ei;
  const int* edst = ei + NE;

  // CSR build (once, reused by all 3 layers)
  hipMemsetAsync(cursor, 0, NN * 4, stream);
  k_count<<<(NE + 255) / 256, 256, 0, stream>>>(edst, cursor);
  k_invdeg<<<(NN + 255) / 256, 256, 0, stream>>>(cursor, inv_deg);
  k_scan1<<<(NN + 1023) / 1024, 256, 0, stream>>>(cursor, row_start, partials);
  k_scan2<<<1, 128, 0, stream>>>(partials, row_start, (NN + 1023) / 1024);
  k_scan3<<<(NN + 255) / 256, 256, 0, stream>>>(row_start, partials);
  hipMemsetAsync(cursor, 0, NN * 4, stream);
  k_fill<<<(NE + 255) / 256, 256, 0, stream>>>(esrc, edst, row_start, cursor, ssrc);

  // bf16 conversions
  const int WK = DH * DIN;
  const int WB = DH * DH;
  k_f2b<<<(WK / 4 + 255) / 256, 256, 0, stream>>>(Wl1, Wl1b, WK);
  k_f2b<<<(WK / 4 + 255) / 256, 256, 0, stream>>>(Wr1, Wr1b, WK);
  k_f2b<<<(WK / 4 + 255) / 256, 256, 0, stream>>>(Ww,  Wwb,  WK);
  k_f2b<<<(WK / 4 + 255) / 256, 256, 0, stream>>>(Ww2, Ww2b, WK);
  k_f2b<<<(WB / 4 + 255) / 256, 256, 0, stream>>>(Wl2, Wl2b, WB);
  k_f2b<<<(WB / 4 + 255) / 256, 256, 0, stream>>>(Wr2, Wr2b, WB);
  k_f2b<<<(WB / 4 + 255) / 256, 256, 0, stream>>>(Wl3, Wl3b, WB);
  k_f2b<<<(WB / 4 + 255) / 256, 256, 0, stream>>>(Wr3, Wr3b, WB);
  k_f2b<<<(NN * DIN / 4 + 255) / 256, 256, 0, stream>>>(x, xb, NN * DIN);

  // agg1 = mean(x) ; gemm1 -> z2 (zb), z3p (z3pb); h1 never materialized
  k_aggb128<<<(NN + 3) / 4, 256, 0, stream>>>(xb, row_start, ssrc, inv_deg, ag1);
  k_gemm1<<<NWG, 256, 0, stream>>>(ag1, xb, Wl1b, Wr1b, Wwb, Ww2b, bl1, bw, bw2, ap,
                                   zb, z3pb);
  // layer 2: agg2 = mean(z2); z3 = prelu(agg2@Wl2 + z2@Wr2 + bl2) + z3p -> zc
  k_aggb512<<<(NN + 3) / 4, 256, 0, stream>>>(zb, row_start, ssrc, inv_deg, agb);
  k_rg23<false><<<NWG, 256, 0, stream>>>(agb, zb, Wl2b, Wr2b, bl2, ap, z3pb, zc);
  // layer 3: agg3 = mean(z3); out = prelu(agg3@Wl3 + z3@Wr3 + bl3) -> f32 d_out
  k_aggb512<<<(NN + 3) / 4, 256, 0, stream>>>(zc, row_start, ssrc, inv_deg, agb);
  k_rg23<true><<<NWG, 256, 0, stream>>>(agb, zc, Wl3b, Wr3b, bl3, ap, nullptr, out);
}

// Round 15
// 980.193 us; speedup vs baseline: 1.0733x; 1.0092x over previous
//
#include <hip/hip_runtime.h>
#include <stddef.h>

#define NN 100000
#define NE 800000
#define DIN 128
#define DH 512
#define MT 782   // ceil(100000/128)
#define NWG (MT * 4)      // 3128 = 8 * 391
#define CPX (NWG / 8)     // 391 chunks per XCD

typedef __attribute__((ext_vector_type(8))) short sh8;
typedef __attribute__((ext_vector_type(4))) float f32x4;

__device__ __forceinline__ unsigned short f2b(float f) {
  unsigned u = __float_as_uint(f);
  return (unsigned short)((u + 0x7FFFu + ((u >> 16) & 1u)) >> 16);
}
__device__ __forceinline__ float b2f(unsigned short s) {
  return __uint_as_float(((unsigned)s) << 16);
}

__device__ __forceinline__ void gload16(const unsigned short* g, unsigned short* l) {
  __builtin_amdgcn_global_load_lds(
      (const __attribute__((address_space(1))) void*)g,
      (__attribute__((address_space(3))) void*)l, 16, 0, 0);
}

#define SCHED_FENCE() __builtin_amdgcn_sched_barrier(0)
#define MEM_FENCE() asm volatile("" ::: "memory")
#define VMCNT(n) asm volatile("s_waitcnt vmcnt(" #n ")" ::: "memory")

// LDS tile layout: 128 rows x 32 bf16 (4 slots of 16B per row).
// Slot swizzle p = s ^ ((row>>1)&3): 16-lane read groups go 8-way -> 2-way (free).
// For all access patterns here (row>>1)&3 is a PER-THREAD CONSTANT:
//   reads  (row = base + i*16 + r16, base%64==0): (r16>>1)&3
//   writes (row = tid>>2 [+64]):                  (tid>>3)&3
// so the swizzle costs zero instructions in the loops (rule #21 both-sides:
// rg23 swizzles its ds_writes; gemm1 pre-swizzles the GLOBAL source column).

// ---------------- CSR build ----------------

__global__ void k_count(const int* __restrict__ dst, int* __restrict__ cnt) {
  int i = blockIdx.x * blockDim.x + threadIdx.x;
  if (i < NE) atomicAdd(&cnt[dst[i]], 1);
}

__global__ void k_invdeg(const int* __restrict__ cnt, float* __restrict__ inv_deg) {
  int i = blockIdx.x * blockDim.x + threadIdx.x;
  if (i < NN) inv_deg[i] = 1.0f / (float)(cnt[i] > 1 ? cnt[i] : 1);
}

__global__ void k_scan1(const int* __restrict__ cnt, int* __restrict__ excl,
                        int* __restrict__ partials) {
  __shared__ int sh[256];
  int tid = threadIdx.x;
  int base = blockIdx.x * 1024 + tid * 4;
  int v[4]; int s = 0;
#pragma unroll
  for (int i = 0; i < 4; i++) { int idx = base + i; v[i] = (idx < NN) ? cnt[idx] : 0; s += v[i]; }
  sh[tid] = s; __syncthreads();
  for (int off = 1; off < 256; off <<= 1) {
    int t = (tid >= off) ? sh[tid - off] : 0;
    __syncthreads();
    sh[tid] += t;
    __syncthreads();
  }
  int run = sh[tid] - s;
#pragma unroll
  for (int i = 0; i < 4; i++) { int idx = base + i; if (idx < NN) excl[idx] = run; run += v[i]; }
  if (tid == 255) partials[blockIdx.x] = sh[255];
}

__global__ void k_scan2(int* __restrict__ partials, int* __restrict__ row_start, int nparts) {
  __shared__ int sh[128];
  int tid = threadIdx.x;
  int v = (tid < nparts) ? partials[tid] : 0;
  sh[tid] = v; __syncthreads();
  for (int off = 1; off < 128; off <<= 1) {
    int t = (tid >= off) ? sh[tid - off] : 0;
    __syncthreads();
    sh[tid] += t;
    __syncthreads();
  }
  if (tid < nparts) partials[tid] = sh[tid] - v;
  if (tid == 127) row_start[NN] = sh[127];
}

__global__ void k_scan3(int* __restrict__ excl, const int* __restrict__ partials) {
  int i = blockIdx.x * blockDim.x + threadIdx.x;
  if (i < NN) excl[i] += partials[i >> 10];
}

__global__ void k_fill(const int* __restrict__ src, const int* __restrict__ dst,
                       const int* __restrict__ row_start, int* __restrict__ cursor,
                       int* __restrict__ ssrc) {
  int i = blockIdx.x * blockDim.x + threadIdx.x;
  if (i < NE) {
    int d = dst[i];
    int pos = atomicAdd(&cursor[d], 1);
    ssrc[row_start[d] + pos] = src[i];
  }
}

// ---------------- f32 -> bf16 convert ----------------

__global__ void k_f2b(const float* __restrict__ src, unsigned short* __restrict__ dst, int n) {
  int i = (blockIdx.x * blockDim.x + threadIdx.x) * 4;
  if (i < n) {
    float4 v = *(const float4*)(src + i);
    ushort4 o;
    o.x = f2b(v.x); o.y = f2b(v.y); o.z = f2b(v.z); o.w = f2b(v.w);
    *(ushort4*)(dst + i) = o;
  }
}

// ---------------- mean aggregation (wave per node, bf16 in/out, f32 accum) ----------------

__global__ __launch_bounds__(256) void k_aggb512(
    const unsigned short* __restrict__ z, const int* __restrict__ rs,
    const int* __restrict__ ssrc, const float* __restrict__ inv_deg,
    unsigned short* __restrict__ agg) {
  int w = (blockIdx.x * blockDim.x + threadIdx.x) >> 6;
  int lane = threadIdx.x & 63;
  if (w >= NN) return;
  int e0 = rs[w], e1 = rs[w + 1];
  float acc[8] = {0, 0, 0, 0, 0, 0, 0, 0};
  int e = e0;
  for (; e + 3 < e1; e += 4) {     // 4 independent 16B gathers in flight
    int s0i = ssrc[e], s1i = ssrc[e + 1], s2i = ssrc[e + 2], s3i = ssrc[e + 3];
    sh8 v0 = *(const sh8*)(z + (size_t)s0i * DH + lane * 8);
    sh8 v1 = *(const sh8*)(z + (size_t)s1i * DH + lane * 8);
    sh8 v2 = *(const sh8*)(z + (size_t)s2i * DH + lane * 8);
    sh8 v3 = *(const sh8*)(z + (size_t)s3i * DH + lane * 8);
#pragma unroll
    for (int j = 0; j < 8; ++j)
      acc[j] += (b2f((unsigned short)v0[j]) + b2f((unsigned short)v1[j])) +
                (b2f((unsigned short)v2[j]) + b2f((unsigned short)v3[j]));
  }
  for (; e < e1; ++e) {
    int sa = ssrc[e];
    sh8 va = *(const sh8*)(z + (size_t)sa * DH + lane * 8);
#pragma unroll
    for (int j = 0; j < 8; ++j) acc[j] += b2f((unsigned short)va[j]);
  }
  float s0 = inv_deg[w];
  sh8 o;
#pragma unroll
  for (int j = 0; j < 8; ++j) o[j] = (short)f2b(acc[j] * s0);
  *(sh8*)(agg + (size_t)w * DH + lane * 8) = o;
}

__global__ __launch_bounds__(256) void k_aggb128(
    const unsigned short* __restrict__ z, const int* __restrict__ rs,
    const int* __restrict__ ssrc, const float* __restrict__ inv_deg,
    unsigned short* __restrict__ agg) {
  int w = (blockIdx.x * blockDim.x + threadIdx.x) >> 6;
  int lane = threadIdx.x & 63;
  if (w >= NN) return;
  int e0 = rs[w], e1 = rs[w + 1];
  float a0 = 0.f, a1 = 0.f;
  int e = e0;
  for (; e + 3 < e1; e += 4) {
    unsigned v0 = *(const unsigned*)(z + (size_t)ssrc[e] * DIN + lane * 2);
    unsigned v1 = *(const unsigned*)(z + (size_t)ssrc[e + 1] * DIN + lane * 2);
    unsigned v2 = *(const unsigned*)(z + (size_t)ssrc[e + 2] * DIN + lane * 2);
    unsigned v3 = *(const unsigned*)(z + (size_t)ssrc[e + 3] * DIN + lane * 2);
    a0 += (b2f((unsigned short)(v0 & 0xFFFFu)) + b2f((unsigned short)(v1 & 0xFFFFu))) +
          (b2f((unsigned short)(v2 & 0xFFFFu)) + b2f((unsigned short)(v3 & 0xFFFFu)));
    a1 += (b2f((unsigned short)(v0 >> 16)) + b2f((unsigned short)(v1 >> 16))) +
          (b2f((unsigned short)(v2 >> 16)) + b2f((unsigned short)(v3 >> 16)));
  }
  for (; e < e1; ++e) {
    unsigned va = *(const unsigned*)(z + (size_t)ssrc[e] * DIN + lane * 2);
    a0 += b2f((unsigned short)(va & 0xFFFFu));
    a1 += b2f((unsigned short)(va >> 16));
  }
  float s0 = inv_deg[w];
  unsigned o = (unsigned)f2b(a0 * s0) | ((unsigned)f2b(a1 * s0) << 16);
  *(unsigned*)(agg + (size_t)w * DIN + lane * 2) = o;
}

// ================= k_gemm1: 128x128 3-buf DMA pipeline + swizzled LDS =========

__device__ __forceinline__ void stage_tile(
    unsigned short* ldsA, unsigned short* ldsB,
    const unsigned short* __restrict__ A, int sA, int m0,
    const unsigned short* __restrict__ B, int sB, int n0,
    int k0, int tid) {
  const int w = tid >> 6, l = tid & 63;
  // pre-swizzled GLOBAL source column: lane l loads logical slot (l&3)^((l>>3)&3)
  const int kc = (((l & 3) ^ ((l >> 3) & 3)) * 8);
  const int rsub = l >> 2;
#pragma unroll
  for (int i = 0; i < 2; ++i) {
    int rl = w * 32 + i * 16 + rsub;
    int ra = m0 + rl; if (ra >= NN) ra = NN - 1;
    gload16(A + (size_t)ra * sA + k0 + kc, ldsA + (size_t)(w * 32 + i * 16) * 32);
    gload16(B + (size_t)(n0 + rl) * sB + k0 + kc, ldsB + (size_t)(w * 32 + i * 16) * 32);
  }
}

// slot argument sw is the PHYSICAL slot (pre-swizzled per thread)
__device__ __forceinline__ void mfma_step(
    const unsigned short* As, const unsigned short* Bs,
    int wr, int wc, int r16, int sw, f32x4 (&acc)[4][4]) {
  sh8 af[4], bf[4];
#pragma unroll
  for (int i = 0; i < 4; ++i)
    af[i] = *(const sh8*)&As[(wr + i * 16 + r16) * 32 + sw * 8];
#pragma unroll
  for (int j = 0; j < 4; ++j)
    bf[j] = *(const sh8*)&Bs[(wc + j * 16 + r16) * 32 + sw * 8];
#pragma unroll
  for (int i = 0; i < 4; ++i)
#pragma unroll
    for (int j = 0; j < 4; ++j)
      acc[i][j] = __builtin_amdgcn_mfma_f32_16x16x32_bf16(af[i], bf[j], acc[i][j], 0, 0, 0);
}

#define PIPE_WAIT(s, S)                 \
  do {                                  \
    if ((s) < (S) - 2) VMCNT(8);        \
    else if ((s) == (S) - 2) VMCNT(4);  \
    else VMCNT(0);                      \
    SCHED_FENCE();                      \
    __builtin_amdgcn_s_barrier();       \
    MEM_FENCE(); SCHED_FENCE();         \
  } while (0)

#define PIPE_END()                      \
  do {                                  \
    SCHED_FENCE();                      \
    __builtin_amdgcn_s_barrier();       \
    MEM_FENCE(); SCHED_FENCE();         \
  } while (0)

__global__ __launch_bounds__(256, 2) void k_gemm1(
    const unsigned short* __restrict__ ag, const unsigned short* __restrict__ xb,
    const unsigned short* __restrict__ Wl1, const unsigned short* __restrict__ Wr1,
    const unsigned short* __restrict__ Ww, const unsigned short* __restrict__ Ww2,
    const float* __restrict__ bl1, const float* __restrict__ bw,
    const float* __restrict__ bw2, const float* __restrict__ aptr,
    unsigned short* __restrict__ z2o, unsigned short* __restrict__ z3po) {
  __shared__ __align__(16) unsigned short As[3][128 * 32];
  __shared__ __align__(16) unsigned short Bs[3][128 * 32];
  const int tid = threadIdx.x;
  const int b = blockIdx.x;
  const int L = (b & 7) * CPX + (b >> 3);
  const int m0 = (L >> 2) * 128, n0 = (L & 3) * 128;
  const int wid = tid >> 6, lane = tid & 63;
  const int r16 = lane & 15, kg = lane >> 4;
  const int swz = kg ^ ((r16 >> 1) & 3);   // physical slot for reads (constant)
  const int wr = (wid >> 1) * 64, wc = (wid & 1) * 64;

  f32x4 a0[4][4], a1[4][4], a2[4][4];
#pragma unroll
  for (int i = 0; i < 4; ++i)
#pragma unroll
    for (int j = 0; j < 4; ++j) { a0[i][j] = 0.f; a1[i][j] = 0.f; a2[i][j] = 0.f; }

  auto stage = [&](int s, int buf) {
    const int seg = s >> 2, k0 = (s & 3) * 32;
    const unsigned short* Ap = (seg == 0) ? ag : xb;
    const unsigned short* Bp = (seg == 0) ? Wl1 : (seg == 1) ? Wr1 : (seg == 2) ? Ww : Ww2;
    stage_tile(As[buf], Bs[buf], Ap, DIN, m0, Bp, DIN, n0, k0, tid);
  };

  stage(0, 0);
  stage(1, 1);
  int cur = 0, nxt = 2;
  for (int s = 0; s < 16; ++s) {
    if (s + 2 < 16) stage(s + 2, nxt);
    PIPE_WAIT(s, 16);
    const int seg = s >> 2;
    __builtin_amdgcn_s_setprio(1);
    if (seg <= 1)      mfma_step(As[cur], Bs[cur], wr, wc, r16, swz, a0);
    else if (seg == 2) mfma_step(As[cur], Bs[cur], wr, wc, r16, swz, a1);
    else               mfma_step(As[cur], Bs[cur], wr, wc, r16, swz, a2);
    __builtin_amdgcn_s_setprio(0);
    PIPE_END();
    cur = (cur == 2) ? 0 : cur + 1;
    nxt = (nxt == 2) ? 0 : nxt + 1;
  }

  const float aval = aptr[0];
#pragma unroll
  for (int i = 0; i < 4; ++i) {
    const int mbase = m0 + wr + i * 16 + kg * 4;
#pragma unroll
    for (int j = 0; j < 4; ++j) {
      const int col = n0 + wc + j * 16 + r16;
      const float b1 = bl1[col], b2 = bw[col], b3 = bw2[col];
#pragma unroll
      for (int r = 0; r < 4; ++r) {
        const int m = mbase + r;
        if (m >= NN) continue;
        float h1 = a0[i][j][r] + b1;
        h1 = h1 > 0.f ? h1 : aval * h1;
        z2o[(size_t)m * DH + col] = f2b(h1 + a1[i][j][r] + b2);
        z3po[(size_t)m * DH + col] = f2b(h1 + a2[i][j][r] + b3);
      }
    }
  }
}

// ========== k_rg23: reg-staged 128x128 GEMM (R9 best) + swizzled LDS ==========

template <bool LAST>
__global__ __launch_bounds__(256) void k_rg23(
    const unsigned short* __restrict__ Aag, const unsigned short* __restrict__ Az,
    const unsigned short* __restrict__ Wl, const unsigned short* __restrict__ Wr,
    const float* __restrict__ bl, const float* __restrict__ aptr,
    const unsigned short* __restrict__ z3p, void* __restrict__ outp) {
  __shared__ __align__(16) unsigned short As[128 * 32];
  __shared__ __align__(16) unsigned short Bs[128 * 32];
  const int tid = threadIdx.x;
  const int b = blockIdx.x;
  const int L = (b & 7) * CPX + (b >> 3);   // XCD-contiguous chunks (R9: FETCH 171 MB)
  const int m0 = (L >> 2) * 128, n0 = (L & 3) * 128;
  const int wid = tid >> 6, lane = tid & 63;
  const int r16 = lane & 15, kg = lane >> 4;
  const int swz = kg ^ ((r16 >> 1) & 3);    // physical slot for reads (constant)
  const int wr = (wid >> 1) * 64, wc = (wid & 1) * 64;
  const int rA = tid >> 2;        // 0..63
  const int cA = (tid & 3) * 8;   // logical k-element offset (global loads)
  const int cW = (((tid & 3) ^ ((tid >> 3) & 3)) * 8);  // physical slot for ds_write

  f32x4 acc[4][4];
#pragma unroll
  for (int i = 0; i < 4; ++i)
#pragma unroll
    for (int j = 0; j < 4; ++j) acc[i][j] = 0.f;

  auto ldA = [&](int s, int r) -> sh8 {
    const unsigned short* A = (s < 16) ? Aag : Az;
    int row = m0 + r; if (row >= NN) row = NN - 1;
    return *(const sh8*)(A + (size_t)row * DH + (s & 15) * 32 + cA);
  };
  auto ldB = [&](int s, int r) -> sh8 {
    const unsigned short* W = (s < 16) ? Wl : Wr;
    return *(const sh8*)(W + (size_t)(n0 + r) * DH + (s & 15) * 32 + cA);
  };

  sh8 va0 = ldA(0, rA), va1 = ldA(0, rA + 64);
  sh8 vb0 = ldB(0, rA), vb1 = ldB(0, rA + 64);

  for (int s = 0; s < 32; ++s) {
    __syncthreads();
    *(sh8*)&As[rA * 32 + cW] = va0;
    *(sh8*)&As[(rA + 64) * 32 + cW] = va1;
    *(sh8*)&Bs[rA * 32 + cW] = vb0;
    *(sh8*)&Bs[(rA + 64) * 32 + cW] = vb1;
    __syncthreads();
    if (s + 1 < 32) {  // prefetch next step into regs, overlaps MFMA below
      va0 = ldA(s + 1, rA); va1 = ldA(s + 1, rA + 64);
      vb0 = ldB(s + 1, rA); vb1 = ldB(s + 1, rA + 64);
    }
    mfma_step(As, Bs, wr, wc, r16, swz, acc);
  }

  const float aval = aptr[0];
  float* outf = (float*)outp;
  unsigned short* outb = (unsigned short*)outp;
#pragma unroll
  for (int i = 0; i < 4; ++i) {
    const int mbase = m0 + wr + i * 16 + kg * 4;
#pragma unroll
    for (int j = 0; j < 4; ++j) {
      const int col = n0 + wc + j * 16 + r16;
      const float bv = bl[col];
#pragma unroll
      for (int r = 0; r < 4; ++r) {
        const int m = mbase + r;
        if (m >= NN) continue;
        float h = acc[i][j][r] + bv;
        h = h > 0.f ? h : aval * h;
        if constexpr (LAST) {
          outf[(size_t)m * DH + col] = h;
        } else {
          outb[(size_t)m * DH + col] = f2b(h + b2f(z3p[(size_t)m * DH + col]));
        }
      }
    }
  }
}

// ---------------- launch ----------------

extern "C" void kernel_launch(void* const* d_in, const int* in_sizes, int n_in,
                              void* d_out, int out_size, void* d_ws, size_t ws_size,
                              hipStream_t stream) {
  const float* x = (const float*)d_in[0];
  const int* ei = (const int*)d_in[1];
  const float* Wl1 = (const float*)d_in[2];
  const float* bl1 = (const float*)d_in[3];
  const float* Wr1 = (const float*)d_in[4];
  const float* Wl2 = (const float*)d_in[5];
  const float* bl2 = (const float*)d_in[6];
  const float* Wr2 = (const float*)d_in[7];
  const float* Wl3 = (const float*)d_in[8];
  const float* bl3 = (const float*)d_in[9];
  const float* Wr3 = (const float*)d_in[10];
  const float* Ww  = (const float*)d_in[11];
  const float* bw  = (const float*)d_in[12];
  const float* Ww2 = (const float*)d_in[13];
  const float* bw2 = (const float*)d_in[14];
  const float* ap  = (const float*)d_in[15];
  float* out = (float*)d_out;

  const size_t MP = 100096;  // 782*128
  char* w = (char*)d_ws;
  size_t off = 0;
  unsigned short* xb   = (unsigned short*)(w + off); off += MP * DIN * 2;
  unsigned short* ag1  = (unsigned short*)(w + off); off += MP * DIN * 2;
  unsigned short* agb  = (unsigned short*)(w + off); off += MP * DH * 2;
  unsigned short* zb   = (unsigned short*)(w + off); off += MP * DH * 2;   // z2
  unsigned short* zc   = (unsigned short*)(w + off); off += MP * DH * 2;   // z3
  unsigned short* z3pb = (unsigned short*)(w + off); off += MP * DH * 2;
  unsigned short* Wl1b = (unsigned short*)(w + off); off += (size_t)DH * DIN * 2;
  unsigned short* Wr1b = (unsigned short*)(w + off); off += (size_t)DH * DIN * 2;
  unsigned short* Wwb  = (unsigned short*)(w + off); off += (size_t)DH * DIN * 2;
  unsigned short* Ww2b = (unsigned short*)(w + off); off += (size_t)DH * DIN * 2;
  unsigned short* Wl2b = (unsigned short*)(w + off); off += (size_t)DH * DH * 2;
  unsigned short* Wr2b = (unsigned short*)(w + off); off += (size_t)DH * DH * 2;
  unsigned short* Wl3b = (unsigned short*)(w + off); off += (size_t)DH * DH * 2;
  unsigned short* Wr3b = (unsigned short*)(w + off); off += (size_t)DH * DH * 2;
  float* inv_deg = (float*)(w + off); off += (size_t)NN * 4;
  int* row_start = (int*)(w + off); off += (size_t)(NN + 1) * 4;
  int* cursor = (int*)(w + off); off += (size_t)NN * 4;
  int* ssrc = (int*)(w + off); off += (size_t)NE * 4;
  int* partials = (int*)(w + off); off += 512;

  const int* esrc = ei;
  const int* edst = ei + NE;

  // CSR build (once, reused by all 3 layers)
  hipMemsetAsync(cursor, 0, NN * 4, stream);
  k_count<<<(NE + 255) / 256, 256, 0, stream>>>(edst, cursor);
  k_invdeg<<<(NN + 255) / 256, 256, 0, stream>>>(cursor, inv_deg);
  k_scan1<<<(NN + 1023) / 1024, 256, 0, stream>>>(cursor, row_start, partials);
  k_scan2<<<1, 128, 0, stream>>>(partials, row_start, (NN + 1023) / 1024);
  k_scan3<<<(NN + 255) / 256, 256, 0, stream>>>(row_start, partials);
  hipMemsetAsync(cursor, 0, NN * 4, stream);
  k_fill<<<(NE + 255) / 256, 256, 0, stream>>>(esrc, edst, row_start, cursor, ssrc);

  // bf16 conversions
  const int WK = DH * DIN;
  const int WB = DH * DH;
  k_f2b<<<(WK / 4 + 255) / 256, 256, 0, stream>>>(Wl1, Wl1b, WK);
  k_f2b<<<(WK / 4 + 255) / 256, 256, 0, stream>>>(Wr1, Wr1b, WK);
  k_f2b<<<(WK / 4 + 255) / 256, 256, 0, stream>>>(Ww,  Wwb,  WK);
  k_f2b<<<(WK / 4 + 255) / 256, 256, 0, stream>>>(Ww2, Ww2b, WK);
  k_f2b<<<(WB / 4 + 255) / 256, 256, 0, stream>>>(Wl2, Wl2b, WB);
  k_f2b<<<(WB / 4 + 255) / 256, 256, 0, stream>>>(Wr2, Wr2b, WB);
  k_f2b<<<(WB / 4 + 255) / 256, 256, 0, stream>>>(Wl3, Wl3b, WB);
  k_f2b<<<(WB / 4 + 255) / 256, 256, 0, stream>>>(Wr3, Wr3b, WB);
  k_f2b<<<(NN * DIN / 4 + 255) / 256, 256, 0, stream>>>(x, xb, NN * DIN);

  // agg1 = mean(x) ; gemm1 -> z2 (zb), z3p (z3pb); h1 never materialized
  k_aggb128<<<(NN + 3) / 4, 256, 0, stream>>>(xb, row_start, ssrc, inv_deg, ag1);
  k_gemm1<<<NWG, 256, 0, stream>>>(ag1, xb, Wl1b, Wr1b, Wwb, Ww2b, bl1, bw, bw2, ap,
                                   zb, z3pb);
  // layer 2: agg2 = mean(z2); z3 = prelu(agg2@Wl2 + z2@Wr2 + bl2) + z3p -> zc
  k_aggb512<<<(NN + 3) / 4, 256, 0, stream>>>(zb, row_start, ssrc, inv_deg, agb);
  k_rg23<false><<<NWG, 256, 0, stream>>>(agb, zb, Wl2b, Wr2b, bl2, ap, z3pb, zc);
  // layer 3: agg3 = mean(z3); out = prelu(agg3@Wl3 + z3@Wr3 + bl3) -> f32 d_out
  k_aggb512<<<(NN + 3) / 4, 256, 0, stream>>>(zc, row_start, ssrc, inv_deg, agb);
  k_rg23<true><<<NWG, 256, 0, stream>>>(agb, zc, Wl3b, Wr3b, bl3, ap, nullptr, out);
}